// Round 6
// baseline (9930.444 us; speedup 1.0000x reference)
//
#include <hip/hip_runtime.h>

// Problem constants (shapes fixed by setup_inputs()).
#define B_ 1024
#define D_ 1024
#define F_ 32768
#define T_ 32
#define KSLOTS 32

// fp16x2 emulation: lo parts are stored scaled by 2^11 so they stay in f16 normal
// range (unscaled lo of xs elements ~1.5e-5 < f16 min normal 6.1e-5 -> flush risk).
#define LO_SCALE     2048.0f
#define LO_INV_SCALE 4.8828125e-4f

typedef _Float16 f16x8  __attribute__((ext_vector_type(8)));
typedef _Float16 f16x4  __attribute__((ext_vector_type(4)));
typedef float    f32x16 __attribute__((ext_vector_type(16)));

// ---------- packed argmax key: (sortable float << 32) | (0xFFFFFFFF - idx) ----------
__device__ __forceinline__ unsigned int fkey(float f) {
    unsigned int u = __float_as_uint(f);
    return (u & 0x80000000u) ? ~u : (u | 0x80000000u);
}
__device__ __forceinline__ unsigned long long packkey(float v, unsigned int n) {
    return ((unsigned long long)fkey(v) << 32) | (unsigned long long)(0xFFFFFFFFu - n);
}

// async global->LDS, 16B per lane. LDS dst is wave-uniform base; HW writes lane l at
// dst + l*16. Global src is per-lane.
__device__ __forceinline__ void async16(const void* g, void* l) {
    __builtin_amdgcn_global_load_lds(
        (const __attribute__((address_space(1))) unsigned int*)g,
        (__attribute__((address_space(3))) unsigned int*)l, 16, 0, 0);
}

__device__ __forceinline__ f32x16 mfma32(f16x8 a, f16x8 b, f32x16 c) {
    return __builtin_amdgcn_mfma_f32_32x32x16_f16(a, b, c, 0, 0, 0);
}

__device__ __forceinline__ void fsplit(float v, _Float16& h, _Float16& l) {
    h = (_Float16)v;
    l = (_Float16)((v - (float)h) * LO_SCALE);
}

// ---------------- one-time XS split: fp32 -> f16 hi + scaled f16 lo ----------------
__global__ __launch_bounds__(256) void split_xs_kernel(
    const float* __restrict__ XS, _Float16* __restrict__ hi, _Float16* __restrict__ lo)
{
    const size_t i = ((size_t)blockIdx.x * 256 + threadIdx.x) * 4;
    const float4 v = *(const float4*)(XS + i);
    f16x4 hv, lv;
    _Float16 h, l;
    fsplit(v.x, h, l); hv[0] = h; lv[0] = l;
    fsplit(v.y, h, l); hv[1] = h; lv[1] = l;
    fsplit(v.z, h, l); hv[2] = h; lv[2] = l;
    fsplit(v.w, h, l); hv[3] = h; lv[3] = l;
    *(f16x4*)(hi + i) = hv;
    *(f16x4*)(lo + i) = lv;
}

// ---------------------------- init: r = x (+f16 split), cnt = 0 ----------------------------
__global__ __launch_bounds__(256) void init_kernel(
    const float* __restrict__ X, float* __restrict__ Rres,
    _Float16* __restrict__ Rhi, _Float16* __restrict__ Rlo,
    int* __restrict__ a_cnt, unsigned long long* __restrict__ amax)
{
    const int b = blockIdx.x, tid = threadIdx.x;
    for (int d = tid; d < D_; d += 256) {
        const float v = X[(size_t)b * D_ + d];
        Rres[(size_t)b * D_ + d] = v;
        _Float16 h, l; fsplit(v, h, l);
        Rhi[(size_t)b * D_ + d] = h;
        Rlo[(size_t)b * D_ + d] = l;
    }
    if (tid == 0) { a_cnt[b] = 0; amax[b] = 0ull; }
}

// ------------------- MFMA fp16x2 GEMM (ip = r @ xs^T) + per-row argmax -------------------
// Tile 128x128, BK=32, 256 threads = 4 waves as 2x2 of 64x64.
// R6 changes vs R5 (keeps R5's counted-vmcnt pipeline + XCD swizzle, both measured wins):
//  (a) MFMA shape 16x16x32 -> 32x32x16: halved instruction count, ~15-20% faster pipe
//      (2382 vs 2075 TF ubench). Per wave-slice: 24 MFMA, 16 ds_read_b128 (same bytes).
//  (b) LDS rotation swizzle: physical 16B k-slot = (logical_slot + row) & 3. R5 reads put
//      16 lanes on 2 bank-slots (rows at 64B stride, same k-octet); rotation spreads any
//      8 consecutive lanes across 8 distinct 4-bank groups. global_load_lds writes
//      linearly, so the swizzle is applied by permuting each lane's GLOBAL source k-slot
//      (skof below, constant per lane) and reading with the same (q+row)&3 (rule #21:
//      both-sides-or-neither). SQ_LDS_BANK_CONFLICT was 16.78M = 65K cyc/CU = 12.5%.
// C/D layout (32x32): col = lane&31, row = (reg&3) + 8*(reg>>2) + 4*(lane>>5).
#define SPL1(H, L, I, V) { _Float16 _h; _Float16 _l; fsplit((V), _h, _l); H[I] = _h; L[I] = _l; }

#define WAIT_VM8()  { asm volatile("s_waitcnt vmcnt(8)" ::: "memory"); }
#define WAIT_VM0()  { asm volatile("s_waitcnt vmcnt(0)" ::: "memory"); }
#define BARRIER_PIN() { __builtin_amdgcn_s_barrier(); __builtin_amdgcn_sched_barrier(0); }

template <bool PRE>
__global__ __launch_bounds__(256, 2) void gemm16_argmax_kernel(
    const _Float16* __restrict__ Ahi, const _Float16* __restrict__ Alo,
    const _Float16* __restrict__ Bhi, const _Float16* __restrict__ Blo,
    const float* __restrict__ XSf,
    unsigned long long* __restrict__ amax)
{
    __shared__ __align__(16) _Float16 As[2][2][128][32];   // [buf][hi/lo][row][k] 32KB
    __shared__ __align__(16) _Float16 Bs[2][2][128][32];   // 32KB
    __shared__ unsigned long long red[128][2];             // 2KB

    const int tid  = threadIdx.x;
    const int wid  = tid >> 6, lane = tid & 63;
    const int orig = (int)blockIdx.x;                  // 0..2047, round-robins XCDs
    const int wgid = (orig & 7) * 256 + (orig >> 3);   // XCD-contiguous chunks (bijective)
    const int m0   = (wgid & 7) * 128;                 // bm fastest within a chunk
    const int n0   = (wgid >> 3) * 128;
    const int wm   = wid >> 1, wn = wid & 1;

    f32x16 acc[2][2], acc2[2][2];
#pragma unroll
    for (int i = 0; i < 2; ++i)
#pragma unroll
        for (int j = 0; j < 2; ++j) {
#pragma unroll
            for (int t = 0; t < 16; ++t) { acc[i][j][t] = 0.f; acc2[i][j][t] = 0.f; }
        }

    // staging: wave w owns rows [w*32, w*32+32) of each tile; 1KB chunk = 16 rows.
    // lane l lands at LDS row (l>>2), phys slot (l&3). Source k-slot is pre-swizzled so
    // LDS phys slot p of row r holds logical slot (p - r) & 3.
    const int srow = wid * 32 + (lane >> 2);
    const int skof = 8 * (((lane & 3) - ((lane >> 2) & 3)) & 3);   // f16 units
    const _Float16* gAh = Ahi + (size_t)(m0 + srow) * D_ + skof;
    const _Float16* gAl = Alo + (size_t)(m0 + srow) * D_ + skof;
    const _Float16* gBh = nullptr;
    const _Float16* gBl = nullptr;
    const float*    gBf = nullptr;
    if constexpr (PRE) {
        gBh = Bhi + (size_t)(n0 + srow) * D_ + skof;
        gBl = Blo + (size_t)(n0 + srow) * D_ + skof;
    } else {
        gBf = XSf + (size_t)(n0 + (tid >> 1)) * D_ + (tid & 1) * 16;
    }

    // fragment read geometry (32x32x16): lane reads row (lane&31) of its tile,
    // logical k-slot q = 2*kh + (lane>>5); phys slot = (q + row) & 3, row&3 = lane&3.
    const int lrow = lane & 31;
    const int qsw0 = 8 * ((0 + (lane >> 5) + (lane & 3)) & 3);   // kh = 0
    const int qsw1 = 8 * ((2 + (lane >> 5) + (lane & 3)) & 3);   // kh = 1

    // ---- helpers ----
    auto stageAB = [&](int bb, int k0) {       // PRE: A+B, 8 async16 per wave
#pragma unroll
        for (int c = 0; c < 2; ++c) {
            const size_t go = (size_t)(c * 16) * D_ + k0;
            const int    ro = wid * 32 + c * 16;
            async16(gAh + go, &As[bb][0][ro][0]);
            async16(gAl + go, &As[bb][1][ro][0]);
            async16(gBh + go, &Bs[bb][0][ro][0]);
            async16(gBl + go, &Bs[bb][1][ro][0]);
        }
    };
    auto stageA = [&](int bb, int k0) {        // !PRE fallback: A only
#pragma unroll
        for (int c = 0; c < 2; ++c) {
            const size_t go = (size_t)(c * 16) * D_ + k0;
            const int    ro = wid * 32 + c * 16;
            async16(gAh + go, &As[bb][0][ro][0]);
            async16(gAl + go, &As[bb][1][ro][0]);
        }
    };
    float4 q0, q1, q2, q3;
    auto loadB = [&](int k0) {
        q0 = *(const float4*)(gBf + k0);
        q1 = *(const float4*)(gBf + k0 + 4);
        q2 = *(const float4*)(gBf + k0 + 8);
        q3 = *(const float4*)(gBf + k0 + 12);
    };
    auto writeB = [&](int bb) {                // split fp32 regs -> f16 hi/lo in LDS
        const int br = tid >> 1;
        const int u  = (tid & 1) * 2;          // logical slots u, u+1
        const int p0 = 8 * (((u + 0) + (br & 3)) & 3);
        const int p1 = 8 * (((u + 1) + (br & 3)) & 3);
        f16x8 h0, l0, h1, l1;
        SPL1(h0, l0, 0, q0.x) SPL1(h0, l0, 1, q0.y) SPL1(h0, l0, 2, q0.z) SPL1(h0, l0, 3, q0.w)
        SPL1(h0, l0, 4, q1.x) SPL1(h0, l0, 5, q1.y) SPL1(h0, l0, 6, q1.z) SPL1(h0, l0, 7, q1.w)
        SPL1(h1, l1, 0, q2.x) SPL1(h1, l1, 1, q2.y) SPL1(h1, l1, 2, q2.z) SPL1(h1, l1, 3, q2.w)
        SPL1(h1, l1, 4, q3.x) SPL1(h1, l1, 5, q3.y) SPL1(h1, l1, 6, q3.z) SPL1(h1, l1, 7, q3.w)
        *(f16x8*)&Bs[bb][0][br][p0] = h0;
        *(f16x8*)&Bs[bb][0][br][p1] = h1;
        *(f16x8*)&Bs[bb][1][br][p0] = l0;
        *(f16x8*)&Bs[bb][1][br][p1] = l1;
    };
    auto compute = [&](int bb) {
        f16x8 ah[2][2], al[2][2], bh[2][2], bl[2][2];   // [tile][kh]
#pragma unroll
        for (int t = 0; t < 2; ++t) {
            const int ra = wm * 64 + t * 32 + lrow;
            const int rb = wn * 64 + t * 32 + lrow;
            ah[t][0] = *(const f16x8*)&As[bb][0][ra][qsw0];
            ah[t][1] = *(const f16x8*)&As[bb][0][ra][qsw1];
            al[t][0] = *(const f16x8*)&As[bb][1][ra][qsw0];
            al[t][1] = *(const f16x8*)&As[bb][1][ra][qsw1];
            bh[t][0] = *(const f16x8*)&Bs[bb][0][rb][qsw0];
            bh[t][1] = *(const f16x8*)&Bs[bb][0][rb][qsw1];
            bl[t][0] = *(const f16x8*)&Bs[bb][1][rb][qsw0];
            bl[t][1] = *(const f16x8*)&Bs[bb][1][rb][qsw1];
        }
#pragma unroll
        for (int i = 0; i < 2; ++i)
#pragma unroll
            for (int j = 0; j < 2; ++j)
#pragma unroll
                for (int kh = 0; kh < 2; ++kh) {
                    acc[i][j]  = mfma32(ah[i][kh], bh[j][kh], acc[i][j]);
                    acc2[i][j] = mfma32(ah[i][kh], bl[j][kh], acc2[i][j]);
                    acc2[i][j] = mfma32(al[i][kh], bh[j][kh], acc2[i][j]);
                }
    };

    if constexpr (PRE) {
        // ---- counted-vmcnt pipeline: loads stay in flight across barriers ----
        stageAB(0, 0);
        WAIT_VM0();
        BARRIER_PIN();
        for (int k0 = 0; k0 < D_; k0 += 64) {
            // slice 0: stage k0+32 -> buf1, wait prev (buf0) loads, compute buf0
            if (k0 + 32 < D_) { stageAB(1, k0 + 32); WAIT_VM8(); }
            else              { WAIT_VM0(); }
            BARRIER_PIN();            // buf0 fully loaded for all waves
            compute(0);
            BARRIER_PIN();            // all waves' buf0 ds_reads retired
            // slice 1: stage k0+64 -> buf0, wait buf1 loads, compute buf1
            if (k0 + 64 < D_) { stageAB(0, k0 + 64); WAIT_VM8(); }
            else              { WAIT_VM0(); }
            BARRIER_PIN();
            compute(1);
            BARRIER_PIN();
        }
    } else {
        // ---- fallback (no pre-split XS): original drain-style dbuf loop ----
        loadB(0); stageA(0, 0); writeB(0);
        __syncthreads();
        for (int k0 = 0; k0 < D_; k0 += 64) {
            if (k0 + 32 < D_) { loadB(k0 + 32); stageA(1, k0 + 32); }
            compute(0);
            if (k0 + 32 < D_) writeB(1);
            __syncthreads();
            if (k0 + 64 < D_) { loadB(k0 + 64); stageA(0, k0 + 64); }
            compute(1);
            if (k0 + 64 < D_) writeB(0);
            __syncthreads();
        }
    }

    // ---- argmax epilogue. 32x32 C/D: col = lane&31, row = (t&3)+8*(t>>2)+4*(lane>>5).
    // For fixed t, lanes 0-31 hold one row (cols 0-31), lanes 32-63 hold row+4.
    // Butterfly with offsets <32 reduces each half independently; lanes 0 and 32 write.
    const unsigned cbase = (unsigned)(n0 + wn * 64 + (lane & 31));
    const int rl4 = 4 * (lane >> 5);
#pragma unroll
    for (int mi = 0; mi < 2; ++mi) {
#pragma unroll
        for (int t = 0; t < 16; ++t) {
            const int rloc = (t & 3) + 8 * (t >> 2) + rl4;
            const float v0 = acc[mi][0][t] + acc2[mi][0][t] * LO_INV_SCALE;
            const float v1 = acc[mi][1][t] + acc2[mi][1][t] * LO_INV_SCALE;
            const unsigned long long k0 = packkey(v0, cbase);
            const unsigned long long k1 = packkey(v1, cbase + 32u);
            unsigned long long best = k0 > k1 ? k0 : k1;
#pragma unroll
            for (int off = 1; off < 32; off <<= 1) {
                const unsigned long long o = __shfl_xor(best, off);
                best = o > best ? o : best;
            }
            if ((lane & 31) == 0)
                red[wm * 64 + mi * 32 + rloc][wn] = best;
        }
    }
    __syncthreads();
    if (tid < 128) {
        const unsigned long long b0 = red[tid][0], b1 = red[tid][1];
        atomicMax(&amax[m0 + tid], b0 > b1 ? b0 : b1);
    }
}

// ----------------- per-row sparse update: select, grad, step, relu, residual -----------------
__global__ __launch_bounds__(256) void update_kernel(
    const float* __restrict__ X, const float* __restrict__ XS,
    float* __restrict__ Rres,
    _Float16* __restrict__ Rhi, _Float16* __restrict__ Rlo,
    int* __restrict__ a_idx, float* __restrict__ a_w, int* __restrict__ a_cnt,
    unsigned long long* __restrict__ amax)
{
    const int b = blockIdx.x;
    const int tid = threadIdx.x;
    __shared__ float s_r[D_];
    __shared__ int   s_idx[33];
    __shared__ float s_w[33];
    __shared__ float s_g[33];
    __shared__ int   s_cnt;
    __shared__ float s_red[8];

    for (int d = tid; d < D_; d += 256) s_r[d] = Rres[(size_t)b * D_ + d];

    if (tid == 0) {
        int cnt = a_cnt[b];
        for (int j = 0; j < cnt; ++j) { s_idx[j] = a_idx[b*KSLOTS + j]; s_w[j] = a_w[b*KSLOTS + j]; }
        unsigned long long key = amax[b];
        int ni = (int)(0xFFFFFFFFu - (unsigned int)(key & 0xFFFFFFFFull));
        bool found = false;
        for (int j = 0; j < cnt; ++j) found = found || (s_idx[j] == ni);
        if (!found) {  // insert keeping indices ascending (matches numpy's sum-over-f order)
            int p = cnt;
            while (p > 0 && s_idx[p-1] > ni) { s_idx[p] = s_idx[p-1]; s_w[p] = s_w[p-1]; --p; }
            s_idx[p] = ni; s_w[p] = 0.f; ++cnt;
        }
        s_cnt = cnt;
    }
    __syncthreads();
    const int cnt = s_cnt;
    const int wave = tid >> 6, lane = tid & 63;

    // grad_j = <r, xs[idx_j]> for each selected atom (one wave per atom, round-robin)
    for (int j = wave; j < cnt; j += 4) {
        const float* xr = XS + (size_t)s_idx[j] * D_;
        float sum = 0.f;
#pragma unroll
        for (int i = 0; i < D_/64; ++i) { int d = lane + (i << 6); sum = fmaf(s_r[d], xr[d], sum); }
        for (int off = 32; off > 0; off >>= 1) sum += __shfl_down(sum, off);
        if (lane == 0) s_g[j] = sum;
    }
    __syncthreads();

    // c = grad @ xs (only over active atoms, ascending index); reduce c.c and c.r
    float cs = 0.f, cr = 0.f;
#pragma unroll
    for (int v = 0; v < 4; ++v) {
        const int d = tid + (v << 8);
        float cv = 0.f;
        for (int j = 0; j < cnt; ++j) cv = fmaf(s_g[j], XS[(size_t)s_idx[j]*D_ + d], cv);
        cs = fmaf(cv, cv, cs);
        cr = fmaf(cv, s_r[d], cr);
    }
    for (int off = 32; off > 0; off >>= 1) { cs += __shfl_down(cs, off); cr += __shfl_down(cr, off); }
    if (lane == 0) { s_red[wave] = cs; s_red[4 + wave] = cr; }
    __syncthreads();

    if (tid == 0) {
        const float cs_t = s_red[0] + s_red[1] + s_red[2] + s_red[3];
        const float cr_t = s_red[4] + s_red[5] + s_red[6] + s_red[7];
        const float ss = cr_t / fmaxf(cs_t, 1e-3f);
        int nc = 0;
        for (int j = 0; j < cnt; ++j) {           // weights = relu(w + ss*grad), drop zeros
            float nw = s_w[j] + ss * s_g[j];
            if (nw > 0.f) { s_idx[nc] = s_idx[j]; s_w[nc] = nw; ++nc; }
        }
        s_cnt = nc;
        a_cnt[b] = nc;
        for (int j = 0; j < nc; ++j) { a_idx[b*KSLOTS + j] = s_idx[j]; a_w[b*KSLOTS + j] = s_w[j]; }
        amax[b] = 0ull;                            // reset for next step's GEMM
    }
    __syncthreads();
    const int nc = s_cnt;

    // fresh residual: r = x - sum_j w_j * xs[idx_j]; also write the f16 hi/lo split
#pragma unroll
    for (int v = 0; v < 4; ++v) {
        const int d = tid + (v << 8);
        float s = 0.f;
        for (int j = 0; j < nc; ++j) s = fmaf(s_w[j], XS[(size_t)s_idx[j]*D_ + d], s);
        const float rv = X[(size_t)b*D_ + d] - s;
        Rres[(size_t)b*D_ + d] = rv;
        _Float16 h, l; fsplit(rv, h, l);
        Rhi[(size_t)b*D_ + d] = h;
        Rlo[(size_t)b*D_ + d] = l;
    }
}

// ----------------- finalize: top_k, decode x/y, losses, write outputs -----------------
__global__ __launch_bounds__(256) void finalize_kernel(
    const float* __restrict__ Y,
    const float* __restrict__ XS, const float* __restrict__ YS,
    const int* __restrict__ a_idx, const float* __restrict__ a_w, const int* __restrict__ a_cnt,
    float* __restrict__ out)
{
    const int b = blockIdx.x, tid = threadIdx.x;
    __shared__ int   s_idx[KSLOTS];
    __shared__ float s_w[KSLOTS];
    __shared__ int   o_idx[KSLOTS];
    __shared__ float o_w[KSLOTS];
    __shared__ float s_red[4];

    if (tid == 0) {
        int cnt = a_cnt[b];
        for (int j = 0; j < cnt; ++j) { s_idx[j] = a_idx[b*KSLOTS + j]; s_w[j] = a_w[b*KSLOTS + j]; }
        // insertion sort: desc weight, ties -> ascending index (lax.top_k semantics)
        for (int i = 1; i < cnt; ++i) {
            int ii = s_idx[i]; float ww = s_w[i];
            int p = i - 1;
            while (p >= 0 && (s_w[p] < ww || (s_w[p] == ww && s_idx[p] > ii))) {
                s_w[p+1] = s_w[p]; s_idx[p+1] = s_idx[p]; --p;
            }
            s_w[p+1] = ww; s_idx[p+1] = ii;
        }
        for (int j = 0; j < cnt; ++j) { o_idx[j] = s_idx[j]; o_w[j] = s_w[j]; }
        // pad remaining slots with the smallest indices whose weight is zero
        int p = cnt, f = 0;
        while (p < KSLOTS) {
            bool member = false;
            for (int j = 0; j < cnt; ++j) member = member || (s_idx[j] == f);
            if (!member) { o_idx[p] = f; o_w[p] = 0.f; ++p; }
            ++f;
        }
    }
    __syncthreads();

    if (tid < KSLOTS) {
        out[(size_t)b*KSLOTS + tid] = o_w[tid];
        out[32768 + (size_t)b*KSLOTS + tid] = (float)o_idx[tid];   // harness reads fp32
    }

    float lsum = 0.f;
    for (int d = tid; d < D_; d += 256) {
        float xr = 0.f, yr = 0.f;
#pragma unroll
        for (int k = 0; k < KSLOTS; ++k) {
            const size_t off = (size_t)o_idx[k] * D_ + d;
            xr = fmaf(o_w[k], XS[off], xr);
            yr = fmaf(o_w[k], YS[off], yr);
        }
        out[65536 + (size_t)b*D_ + d] = xr;
        out[65536 + 1048576 + (size_t)b*D_ + d] = yr;
        const float e = yr - Y[(size_t)b*D_ + d];
        lsum = fmaf(e, e, lsum);
    }
    const int wave = tid >> 6, lane = tid & 63;
    for (int off = 32; off > 0; off >>= 1) lsum += __shfl_down(lsum, off);
    if (lane == 0) s_red[wave] = lsum;
    __syncthreads();
    if (tid == 0) out[65536 + 2097152 + b] = s_red[0] + s_red[1] + s_red[2] + s_red[3];
}

extern "C" void kernel_launch(void* const* d_in, const int* in_sizes, int n_in,
                              void* d_out, int out_size, void* d_ws, size_t ws_size,
                              hipStream_t stream) {
    (void)in_sizes; (void)n_in; (void)out_size;
    const float* x  = (const float*)d_in[0];
    const float* y  = (const float*)d_in[1];
    const float* xs = (const float*)d_in[2];
    const float* ys = (const float*)d_in[3];
    // d_in[4] = target_l0 (hardcoded 32; shapes are fixed)
    float* out = (float*)d_out;

    // workspace layout:
    //   0        Rres fp32            4 MB
    //   4 MB     Rhi  f16             2 MB
    //   6 MB     Rlo  f16 (scaled)    2 MB
    //   8 MB     amax                 8 KB
    //   +8K      a_cnt                4 KB
    //   +12K     a_idx              128 KB
    //   +140K    a_w                128 KB
    //   16 MB    XShi f16            64 MB   (only if ws_size >= 144 MB)
    //   80 MB    XSlo f16 (scaled)   64 MB
    char* ws = (char*)d_ws;
    float*              Rres  = (float*)(ws);
    _Float16*           Rhi   = (_Float16*)(ws + ((size_t)4 << 20));
    _Float16*           Rlo   = (_Float16*)(ws + ((size_t)6 << 20));
    unsigned long long* amax  = (unsigned long long*)(ws + ((size_t)8 << 20));
    int*                a_cnt = (int*)(ws + ((size_t)8 << 20) + 8192);
    int*                a_idx = (int*)(ws + ((size_t)8 << 20) + 8192 + 4096);
    float*              a_w   = (float*)(ws + ((size_t)8 << 20) + 8192 + 4096 + 131072);
    _Float16*           XShi  = (_Float16*)(ws + ((size_t)16 << 20));
    _Float16*           XSlo  = (_Float16*)(ws + ((size_t)80 << 20));
    const bool big = ws_size >= ((size_t)144 << 20);

    if (big) split_xs_kernel<<<(F_ * D_) / 1024, 256, 0, stream>>>(xs, XShi, XSlo);
    init_kernel<<<B_, 256, 0, stream>>>(x, Rres, Rhi, Rlo, a_cnt, amax);

    for (int t = 0; t < T_; ++t) {
        if (big)
            gemm16_argmax_kernel<true ><<<dim3(2048), 256, 0, stream>>>(Rhi, Rlo, XShi, XSlo, xs, amax);
        else
            gemm16_argmax_kernel<false><<<dim3(2048), 256, 0, stream>>>(Rhi, Rlo, nullptr, nullptr, xs, amax);
        update_kernel<<<B_, 256, 0, stream>>>(x, xs, Rres, Rhi, Rlo, a_idx, a_w, a_cnt, amax);
    }
    finalize_kernel<<<B_, 256, 0, stream>>>(y, xs, ys, a_idx, a_w, a_cnt, out);
}

// Round 7
// 7822.362 us; speedup vs baseline: 1.2695x; 1.2695x over previous
//
#include <hip/hip_runtime.h>

// Problem constants (shapes fixed by setup_inputs()).
#define B_ 1024
#define D_ 1024
#define F_ 32768
#define T_ 32
#define KSLOTS 32

// fp16x2 emulation: lo parts are stored scaled by 2^11 so they stay in f16 normal
// range (unscaled lo of xs elements ~1.5e-5 < f16 min normal 6.1e-5 -> flush risk).
#define LO_SCALE     2048.0f
#define LO_INV_SCALE 4.8828125e-4f

typedef _Float16 f16x8 __attribute__((ext_vector_type(8)));
typedef _Float16 f16x4 __attribute__((ext_vector_type(4)));
typedef float    f32x4 __attribute__((ext_vector_type(4)));

// ---------- packed argmax key: (sortable float << 32) | (0xFFFFFFFF - idx) ----------
__device__ __forceinline__ unsigned int fkey(float f) {
    unsigned int u = __float_as_uint(f);
    return (u & 0x80000000u) ? ~u : (u | 0x80000000u);
}
__device__ __forceinline__ unsigned long long packkey(float v, unsigned int n) {
    return ((unsigned long long)fkey(v) << 32) | (unsigned long long)(0xFFFFFFFFu - n);
}

// async global->LDS, 16B per lane. LDS dst is wave-uniform base; HW writes lane l at
// dst + l*16. Global src is per-lane.
__device__ __forceinline__ void async16(const void* g, void* l) {
    __builtin_amdgcn_global_load_lds(
        (const __attribute__((address_space(1))) unsigned int*)g,
        (__attribute__((address_space(3))) unsigned int*)l, 16, 0, 0);
}

__device__ __forceinline__ f32x4 mfma16(f16x8 a, f16x8 b, f32x4 c) {
    return __builtin_amdgcn_mfma_f32_16x16x32_f16(a, b, c, 0, 0, 0);
}

__device__ __forceinline__ void fsplit(float v, _Float16& h, _Float16& l) {
    h = (_Float16)v;
    l = (_Float16)((v - (float)h) * LO_SCALE);
}

// ---------------- one-time XS split: fp32 -> f16 hi + scaled f16 lo ----------------
__global__ __launch_bounds__(256) void split_xs_kernel(
    const float* __restrict__ XS, _Float16* __restrict__ hi, _Float16* __restrict__ lo)
{
    const size_t i = ((size_t)blockIdx.x * 256 + threadIdx.x) * 4;
    const float4 v = *(const float4*)(XS + i);
    f16x4 hv, lv;
    _Float16 h, l;
    fsplit(v.x, h, l); hv[0] = h; lv[0] = l;
    fsplit(v.y, h, l); hv[1] = h; lv[1] = l;
    fsplit(v.z, h, l); hv[2] = h; lv[2] = l;
    fsplit(v.w, h, l); hv[3] = h; lv[3] = l;
    *(f16x4*)(hi + i) = hv;
    *(f16x4*)(lo + i) = lv;
}

// ---------------------------- init: r = x (+f16 split), cnt = 0 ----------------------------
__global__ __launch_bounds__(256) void init_kernel(
    const float* __restrict__ X, float* __restrict__ Rres,
    _Float16* __restrict__ Rhi, _Float16* __restrict__ Rlo,
    int* __restrict__ a_cnt, unsigned long long* __restrict__ amax)
{
    const int b = blockIdx.x, tid = threadIdx.x;
    const size_t d4 = (size_t)b * D_ + tid * 4;
    const float4 v = *(const float4*)(X + d4);
    *(float4*)(Rres + d4) = v;
    f16x4 hv, lv; _Float16 h, l;
    fsplit(v.x, h, l); hv[0] = h; lv[0] = l;
    fsplit(v.y, h, l); hv[1] = h; lv[1] = l;
    fsplit(v.z, h, l); hv[2] = h; lv[2] = l;
    fsplit(v.w, h, l); hv[3] = h; lv[3] = l;
    *(f16x4*)(Rhi + d4) = hv;
    *(f16x4*)(Rlo + d4) = lv;
    if (tid == 0) { a_cnt[b] = 0; amax[b] = 0ull; }
}

// ------------------- MFMA fp16x2 GEMM (ip = r @ xs^T) + per-row argmax -------------------
// Tile 128x128, BK=32, 256 threads = 4 waves as 2x2 of 64x64.
// R7 = EXACT R5 gemm (verified 219us / MfmaUtil 43.5 / conflicts 16.78M).
// R6's 32x32+rotation-swizzle regressed (304us, conflicts 3x) -> reverted; two failed
// LDS-layout predictions in a row means no more LDS micro-edits without a validated
// bank model. Counted-vmcnt pipeline (T4) + XCD-bijective swizzle retained.
#define SPL1(H, L, I, V) { _Float16 _h; _Float16 _l; fsplit((V), _h, _l); H[I] = _h; L[I] = _l; }

#define WAIT_VM8()  { asm volatile("s_waitcnt vmcnt(8)" ::: "memory"); }
#define WAIT_VM0()  { asm volatile("s_waitcnt vmcnt(0)" ::: "memory"); }
#define BARRIER_PIN() { __builtin_amdgcn_s_barrier(); __builtin_amdgcn_sched_barrier(0); }

template <bool PRE>
__global__ __launch_bounds__(256, 2) void gemm16_argmax_kernel(
    const _Float16* __restrict__ Ahi, const _Float16* __restrict__ Alo,
    const _Float16* __restrict__ Bhi, const _Float16* __restrict__ Blo,
    const float* __restrict__ XSf,
    unsigned long long* __restrict__ amax)
{
    __shared__ __align__(16) _Float16 As[2][2][128][32];   // [buf][hi/lo][row][k] 32KB
    __shared__ __align__(16) _Float16 Bs[2][2][128][32];   // 32KB
    __shared__ unsigned long long red[128][2];             // 2KB

    const int tid  = threadIdx.x;
    const int wid  = tid >> 6, lane = tid & 63;
    const int orig = (int)blockIdx.x;                  // 0..2047, round-robins XCDs
    const int wgid = (orig & 7) * 256 + (orig >> 3);   // XCD-contiguous chunks (bijective)
    const int m0   = (wgid & 7) * 128;                 // bm fastest within a chunk
    const int n0   = (wgid >> 3) * 128;
    const int wm   = wid >> 1, wn = wid & 1;

    f32x4 acc[4][4], acc2[4][4];
#pragma unroll
    for (int i = 0; i < 4; ++i)
#pragma unroll
        for (int j = 0; j < 4; ++j) {
            acc[i][j]  = (f32x4){0.f, 0.f, 0.f, 0.f};
            acc2[i][j] = (f32x4){0.f, 0.f, 0.f, 0.f};
        }

    // staging: wave w owns rows [w*32, w*32+32) of each tile; 1KB chunk = 16 rows.
    // lane l sources row (l>>2), 16B k-slot (l&3) -> matches HW's dst + l*16 layout.
    const int srow = wid * 32 + (lane >> 2);
    const int skof = (lane & 3) * 8;
    const _Float16* gAh = Ahi + (size_t)(m0 + srow) * D_ + skof;
    const _Float16* gAl = Alo + (size_t)(m0 + srow) * D_ + skof;
    const _Float16* gBh = nullptr;
    const _Float16* gBl = nullptr;
    const float*    gBf = nullptr;
    if constexpr (PRE) {
        gBh = Bhi + (size_t)(n0 + srow) * D_ + skof;
        gBl = Blo + (size_t)(n0 + srow) * D_ + skof;
    } else {
        gBf = XSf + (size_t)(n0 + (tid >> 1)) * D_ + (tid & 1) * 16;
    }

    const int lrow = lane & 15;          // fragment row/col within 16x16
    const int lk   = (lane >> 4) * 8;    // k octet

    // ---- helpers ----
    auto stageAB = [&](int bb, int k0) {       // PRE: A+B, 8 async16 per wave
#pragma unroll
        for (int c = 0; c < 2; ++c) {
            const size_t go = (size_t)(c * 16) * D_ + k0;
            const int    ro = wid * 32 + c * 16;
            async16(gAh + go, &As[bb][0][ro][0]);
            async16(gAl + go, &As[bb][1][ro][0]);
            async16(gBh + go, &Bs[bb][0][ro][0]);
            async16(gBl + go, &Bs[bb][1][ro][0]);
        }
    };
    auto stageA = [&](int bb, int k0) {        // !PRE fallback: A only
#pragma unroll
        for (int c = 0; c < 2; ++c) {
            const size_t go = (size_t)(c * 16) * D_ + k0;
            const int    ro = wid * 32 + c * 16;
            async16(gAh + go, &As[bb][0][ro][0]);
            async16(gAl + go, &As[bb][1][ro][0]);
        }
    };
    float4 q0, q1, q2, q3;
    auto loadB = [&](int k0) {
        q0 = *(const float4*)(gBf + k0);
        q1 = *(const float4*)(gBf + k0 + 4);
        q2 = *(const float4*)(gBf + k0 + 8);
        q3 = *(const float4*)(gBf + k0 + 12);
    };
    auto writeB = [&](int bb) {                // split fp32 regs -> f16 hi/lo in LDS
        const int br = tid >> 1, bq = (tid & 1) * 16;
        f16x8 h0, l0, h1, l1;
        SPL1(h0, l0, 0, q0.x) SPL1(h0, l0, 1, q0.y) SPL1(h0, l0, 2, q0.z) SPL1(h0, l0, 3, q0.w)
        SPL1(h0, l0, 4, q1.x) SPL1(h0, l0, 5, q1.y) SPL1(h0, l0, 6, q1.z) SPL1(h0, l0, 7, q1.w)
        SPL1(h1, l1, 0, q2.x) SPL1(h1, l1, 1, q2.y) SPL1(h1, l1, 2, q2.z) SPL1(h1, l1, 3, q2.w)
        SPL1(h1, l1, 4, q3.x) SPL1(h1, l1, 5, q3.y) SPL1(h1, l1, 6, q3.z) SPL1(h1, l1, 7, q3.w)
        *(f16x8*)&Bs[bb][0][br][bq]     = h0;
        *(f16x8*)&Bs[bb][0][br][bq + 8] = h1;
        *(f16x8*)&Bs[bb][1][br][bq]     = l0;
        *(f16x8*)&Bs[bb][1][br][bq + 8] = l1;
    };
    auto compute = [&](int bb) {
        f16x8 ah[4], al[4], bh[4], bl[4];
#pragma unroll
        for (int i = 0; i < 4; ++i) {
            ah[i] = *(const f16x8*)&As[bb][0][wm * 64 + i * 16 + lrow][lk];
            al[i] = *(const f16x8*)&As[bb][1][wm * 64 + i * 16 + lrow][lk];
            bh[i] = *(const f16x8*)&Bs[bb][0][wn * 64 + i * 16 + lrow][lk];
            bl[i] = *(const f16x8*)&Bs[bb][1][wn * 64 + i * 16 + lrow][lk];
        }
#pragma unroll
        for (int i = 0; i < 4; ++i)
#pragma unroll
            for (int j = 0; j < 4; ++j) {
                acc[i][j]  = mfma16(ah[i], bh[j], acc[i][j]);
                acc2[i][j] = mfma16(ah[i], bl[j], acc2[i][j]);
                acc2[i][j] = mfma16(al[i], bh[j], acc2[i][j]);
            }
    };

    if constexpr (PRE) {
        // ---- counted-vmcnt pipeline: loads stay in flight across barriers ----
        stageAB(0, 0);
        WAIT_VM0();
        BARRIER_PIN();
        for (int k0 = 0; k0 < D_; k0 += 64) {
            // slice 0: stage k0+32 -> buf1, wait prev (buf0) loads, compute buf0
            if (k0 + 32 < D_) { stageAB(1, k0 + 32); WAIT_VM8(); }
            else              { WAIT_VM0(); }
            BARRIER_PIN();            // buf0 fully loaded for all waves
            compute(0);
            BARRIER_PIN();            // all waves' buf0 ds_reads retired
            // slice 1: stage k0+64 -> buf0, wait buf1 loads, compute buf1
            if (k0 + 64 < D_) { stageAB(0, k0 + 64); WAIT_VM8(); }
            else              { WAIT_VM0(); }
            BARRIER_PIN();
            compute(1);
            BARRIER_PIN();
        }
    } else {
        // ---- fallback (no pre-split XS): original drain-style dbuf loop ----
        loadB(0); stageA(0, 0); writeB(0);
        __syncthreads();
        for (int k0 = 0; k0 < D_; k0 += 64) {
            if (k0 + 32 < D_) { loadB(k0 + 32); stageA(1, k0 + 32); }
            compute(0);
            if (k0 + 32 < D_) writeB(1);
            __syncthreads();
            if (k0 + 64 < D_) { loadB(k0 + 64); stageA(0, k0 + 64); }
            compute(1);
            if (k0 + 64 < D_) writeB(0);
            __syncthreads();
        }
    }

    // ---- argmax epilogue. C/D layout: col = lane&15, row = (lane>>4)*4 + reg. ----
    const unsigned cb = (unsigned)(n0 + wn * 64 + (lane & 15));
#pragma unroll
    for (int mi = 0; mi < 4; ++mi) {
#pragma unroll
        for (int r = 0; r < 4; ++r) {
            unsigned long long best = 0ull;
#pragma unroll
            for (int j = 0; j < 4; ++j) {
                const float v = acc[mi][j][r] + acc2[mi][j][r] * LO_INV_SCALE;
                const unsigned long long key = packkey(v, cb + (unsigned)(j * 16));
                best = key > best ? key : best;
            }
            // reduce over the 16 lanes sharing this row set (lane>>4 fixed)
#pragma unroll
            for (int off = 1; off < 16; off <<= 1) {
                const unsigned long long o = __shfl_xor(best, off);
                best = o > best ? o : best;
            }
            if ((lane & 15) == 0)
                red[wm * 64 + mi * 16 + ((lane >> 4) << 2) + r][wn] = best;
        }
    }
    __syncthreads();
    if (tid < 128) {
        const unsigned long long b0 = red[tid][0], b1 = red[tid][1];
        atomicMax(&amax[m0 + tid], b0 > b1 ? b0 : b1);
    }
}

// ----------------- per-row sparse update: select, grad, step, relu, residual -----------------
// R7: all three D-passes vectorized to float4 (16B/lane, G13). Per-element math identical;
// only the wave-dot accumulation order shifts (~1e-6 fp noise, inside current margin).
__global__ __launch_bounds__(256) void update_kernel(
    const float* __restrict__ X, const float* __restrict__ XS,
    float* __restrict__ Rres,
    _Float16* __restrict__ Rhi, _Float16* __restrict__ Rlo,
    int* __restrict__ a_idx, float* __restrict__ a_w, int* __restrict__ a_cnt,
    unsigned long long* __restrict__ amax)
{
    const int b = blockIdx.x;
    const int tid = threadIdx.x;
    __shared__ float s_r[D_];
    __shared__ int   s_idx[33];
    __shared__ float s_w[33];
    __shared__ float s_g[33];
    __shared__ int   s_cnt;
    __shared__ float s_red[8];

    *(float4*)&s_r[tid * 4] = *(const float4*)(Rres + (size_t)b * D_ + tid * 4);

    if (tid == 0) {
        int cnt = a_cnt[b];
        for (int j = 0; j < cnt; ++j) { s_idx[j] = a_idx[b*KSLOTS + j]; s_w[j] = a_w[b*KSLOTS + j]; }
        unsigned long long key = amax[b];
        int ni = (int)(0xFFFFFFFFu - (unsigned int)(key & 0xFFFFFFFFull));
        bool found = false;
        for (int j = 0; j < cnt; ++j) found = found || (s_idx[j] == ni);
        if (!found) {  // insert keeping indices ascending (matches numpy's sum-over-f order)
            int p = cnt;
            while (p > 0 && s_idx[p-1] > ni) { s_idx[p] = s_idx[p-1]; s_w[p] = s_w[p-1]; --p; }
            s_idx[p] = ni; s_w[p] = 0.f; ++cnt;
        }
        s_cnt = cnt;
    }
    __syncthreads();
    const int cnt = s_cnt;
    const int wave = tid >> 6, lane = tid & 63;

    // grad_j = <r, xs[idx_j]> for each selected atom (one wave per atom, round-robin)
    for (int j = wave; j < cnt; j += 4) {
        const float* xr = XS + (size_t)s_idx[j] * D_;
        float sum = 0.f;
#pragma unroll
        for (int i = 0; i < 4; ++i) {
            const int d = lane * 4 + i * 256;
            const float4 xv = *(const float4*)(xr + d);
            const float4 rv = *(const float4*)(&s_r[d]);
            sum = fmaf(rv.x, xv.x, sum); sum = fmaf(rv.y, xv.y, sum);
            sum = fmaf(rv.z, xv.z, sum); sum = fmaf(rv.w, xv.w, sum);
        }
        for (int off = 32; off > 0; off >>= 1) sum += __shfl_down(sum, off);
        if (lane == 0) s_g[j] = sum;
    }
    __syncthreads();

    // c = grad @ xs (only over active atoms, ascending index); reduce c.c and c.r
    const int d4 = tid * 4;
    float cs = 0.f, cr = 0.f;
    {
        float4 cv = {0.f, 0.f, 0.f, 0.f};
        for (int j = 0; j < cnt; ++j) {
            const float g = s_g[j];
            const float4 xv = *(const float4*)(XS + (size_t)s_idx[j] * D_ + d4);
            cv.x = fmaf(g, xv.x, cv.x); cv.y = fmaf(g, xv.y, cv.y);
            cv.z = fmaf(g, xv.z, cv.z); cv.w = fmaf(g, xv.w, cv.w);
        }
        const float4 rv = *(const float4*)(&s_r[d4]);
        cs = fmaf(cv.x, cv.x, cs); cr = fmaf(cv.x, rv.x, cr);
        cs = fmaf(cv.y, cv.y, cs); cr = fmaf(cv.y, rv.y, cr);
        cs = fmaf(cv.z, cv.z, cs); cr = fmaf(cv.z, rv.z, cr);
        cs = fmaf(cv.w, cv.w, cs); cr = fmaf(cv.w, rv.w, cr);
    }
    for (int off = 32; off > 0; off >>= 1) { cs += __shfl_down(cs, off); cr += __shfl_down(cr, off); }
    if (lane == 0) { s_red[wave] = cs; s_red[4 + wave] = cr; }
    __syncthreads();

    if (tid == 0) {
        const float cs_t = s_red[0] + s_red[1] + s_red[2] + s_red[3];
        const float cr_t = s_red[4] + s_red[5] + s_red[6] + s_red[7];
        const float ss = cr_t / fmaxf(cs_t, 1e-3f);
        int nc = 0;
        for (int j = 0; j < cnt; ++j) {           // weights = relu(w + ss*grad), drop zeros
            float nw = s_w[j] + ss * s_g[j];
            if (nw > 0.f) { s_idx[nc] = s_idx[j]; s_w[nc] = nw; ++nc; }
        }
        s_cnt = nc;
        a_cnt[b] = nc;
        for (int j = 0; j < nc; ++j) { a_idx[b*KSLOTS + j] = s_idx[j]; a_w[b*KSLOTS + j] = s_w[j]; }
        amax[b] = 0ull;                            // reset for next step's GEMM
    }
    __syncthreads();
    const int nc = s_cnt;

    // fresh residual: r = x - sum_j w_j * xs[idx_j]; also write the f16 hi/lo split
    {
        float4 s = {0.f, 0.f, 0.f, 0.f};
        for (int j = 0; j < nc; ++j) {
            const float w = s_w[j];
            const float4 xv = *(const float4*)(XS + (size_t)s_idx[j] * D_ + d4);
            s.x = fmaf(w, xv.x, s.x); s.y = fmaf(w, xv.y, s.y);
            s.z = fmaf(w, xv.z, s.z); s.w = fmaf(w, xv.w, s.w);
        }
        const size_t o = (size_t)b * D_ + d4;
        const float4 xv = *(const float4*)(X + o);
        float4 rv;
        rv.x = xv.x - s.x; rv.y = xv.y - s.y; rv.z = xv.z - s.z; rv.w = xv.w - s.w;
        *(float4*)(Rres + o) = rv;
        f16x4 hv, lv; _Float16 h, l;
        fsplit(rv.x, h, l); hv[0] = h; lv[0] = l;
        fsplit(rv.y, h, l); hv[1] = h; lv[1] = l;
        fsplit(rv.z, h, l); hv[2] = h; lv[2] = l;
        fsplit(rv.w, h, l); hv[3] = h; lv[3] = l;
        *(f16x4*)(Rhi + o) = hv;
        *(f16x4*)(Rlo + o) = lv;
    }
}

// ----------------- finalize: top_k, decode x/y, losses, write outputs -----------------
__global__ __launch_bounds__(256) void finalize_kernel(
    const float* __restrict__ Y,
    const float* __restrict__ XS, const float* __restrict__ YS,
    const int* __restrict__ a_idx, const float* __restrict__ a_w, const int* __restrict__ a_cnt,
    float* __restrict__ out)
{
    const int b = blockIdx.x, tid = threadIdx.x;
    __shared__ int   s_idx[KSLOTS];
    __shared__ float s_w[KSLOTS];
    __shared__ int   o_idx[KSLOTS];
    __shared__ float o_w[KSLOTS];
    __shared__ float s_red[4];

    if (tid == 0) {
        int cnt = a_cnt[b];
        for (int j = 0; j < cnt; ++j) { s_idx[j] = a_idx[b*KSLOTS + j]; s_w[j] = a_w[b*KSLOTS + j]; }
        // insertion sort: desc weight, ties -> ascending index (lax.top_k semantics)
        for (int i = 1; i < cnt; ++i) {
            int ii = s_idx[i]; float ww = s_w[i];
            int p = i - 1;
            while (p >= 0 && (s_w[p] < ww || (s_w[p] == ww && s_idx[p] > ii))) {
                s_w[p+1] = s_w[p]; s_idx[p+1] = s_idx[p]; --p;
            }
            s_w[p+1] = ww; s_idx[p+1] = ii;
        }
        for (int j = 0; j < cnt; ++j) { o_idx[j] = s_idx[j]; o_w[j] = s_w[j]; }
        // pad remaining slots with the smallest indices whose weight is zero
        int p = cnt, f = 0;
        while (p < KSLOTS) {
            bool member = false;
            for (int j = 0; j < cnt; ++j) member = member || (s_idx[j] == f);
            if (!member) { o_idx[p] = f; o_w[p] = 0.f; ++p; }
            ++f;
        }
    }
    __syncthreads();

    if (tid < KSLOTS) {
        out[(size_t)b*KSLOTS + tid] = o_w[tid];
        out[32768 + (size_t)b*KSLOTS + tid] = (float)o_idx[tid];   // harness reads fp32
    }

    // decode pass: float4 (one 4-elem chunk per thread; 256*4 = 1024 = D_)
    const int d4 = tid * 4;
    float4 xr = {0.f, 0.f, 0.f, 0.f}, yr = {0.f, 0.f, 0.f, 0.f};
#pragma unroll
    for (int k = 0; k < KSLOTS; ++k) {
        const float w = o_w[k];
        const size_t off = (size_t)o_idx[k] * D_ + d4;
        const float4 xv = *(const float4*)(XS + off);
        const float4 yv = *(const float4*)(YS + off);
        xr.x = fmaf(w, xv.x, xr.x); xr.y = fmaf(w, xv.y, xr.y);
        xr.z = fmaf(w, xv.z, xr.z); xr.w = fmaf(w, xv.w, xr.w);
        yr.x = fmaf(w, yv.x, yr.x); yr.y = fmaf(w, yv.y, yr.y);
        yr.z = fmaf(w, yv.z, yr.z); yr.w = fmaf(w, yv.w, yr.w);
    }
    *(float4*)(out + 65536 + (size_t)b*D_ + d4) = xr;
    *(float4*)(out + 65536 + 1048576 + (size_t)b*D_ + d4) = yr;
    const float4 yv = *(const float4*)(Y + (size_t)b*D_ + d4);
    float lsum = 0.f;
    {
        const float e0 = yr.x - yv.x, e1 = yr.y - yv.y, e2 = yr.z - yv.z, e3 = yr.w - yv.w;
        lsum = fmaf(e0, e0, lsum); lsum = fmaf(e1, e1, lsum);
        lsum = fmaf(e2, e2, lsum); lsum = fmaf(e3, e3, lsum);
    }
    const int wave = tid >> 6, lane = tid & 63;
    for (int off = 32; off > 0; off >>= 1) lsum += __shfl_down(lsum, off);
    if (lane == 0) s_red[wave] = lsum;
    __syncthreads();
    if (tid == 0) out[65536 + 2097152 + b] = s_red[0] + s_red[1] + s_red[2] + s_red[3];
}

extern "C" void kernel_launch(void* const* d_in, const int* in_sizes, int n_in,
                              void* d_out, int out_size, void* d_ws, size_t ws_size,
                              hipStream_t stream) {
    (void)in_sizes; (void)n_in; (void)out_size;
    const float* x  = (const float*)d_in[0];
    const float* y  = (const float*)d_in[1];
    const float* xs = (const float*)d_in[2];
    const float* ys = (const float*)d_in[3];
    // d_in[4] = target_l0 (hardcoded 32; shapes are fixed)
    float* out = (float*)d_out;

    // workspace layout:
    //   0        Rres fp32            4 MB
    //   4 MB     Rhi  f16             2 MB
    //   6 MB     Rlo  f16 (scaled)    2 MB
    //   8 MB     amax                 8 KB
    //   +8K      a_cnt                4 KB
    //   +12K     a_idx              128 KB
    //   +140K    a_w                128 KB
    //   16 MB    XShi f16            64 MB   (only if ws_size >= 144 MB)
    //   80 MB    XSlo f16 (scaled)   64 MB
    char* ws = (char*)d_ws;
    float*              Rres  = (float*)(ws);
    _Float16*           Rhi   = (_Float16*)(ws + ((size_t)4 << 20));
    _Float16*           Rlo   = (_Float16*)(ws + ((size_t)6 << 20));
    unsigned long long* amax  = (unsigned long long*)(ws + ((size_t)8 << 20));
    int*                a_cnt = (int*)(ws + ((size_t)8 << 20) + 8192);
    int*                a_idx = (int*)(ws + ((size_t)8 << 20) + 8192 + 4096);
    float*              a_w   = (float*)(ws + ((size_t)8 << 20) + 8192 + 4096 + 131072);
    _Float16*           XShi  = (_Float16*)(ws + ((size_t)16 << 20));
    _Float16*           XSlo  = (_Float16*)(ws + ((size_t)80 << 20));
    const bool big = ws_size >= ((size_t)144 << 20);

    if (big) split_xs_kernel<<<(F_ * D_) / 1024, 256, 0, stream>>>(xs, XShi, XSlo);
    init_kernel<<<B_, 256, 0, stream>>>(x, Rres, Rhi, Rlo, a_cnt, amax);

    for (int t = 0; t < T_; ++t) {
        if (big)
            gemm16_argmax_kernel<true ><<<dim3(2048), 256, 0, stream>>>(Rhi, Rlo, XShi, XSlo, xs, amax);
        else
            gemm16_argmax_kernel<false><<<dim3(2048), 256, 0, stream>>>(Rhi, Rlo, nullptr, nullptr, xs, amax);
        update_kernel<<<B_, 256, 0, stream>>>(x, xs, Rres, Rhi, Rlo, a_idx, a_w, a_cnt, amax);
    }
    finalize_kernel<<<B_, 256, 0, stream>>>(y, xs, ys, a_idx, a_w, a_cnt, out);
}

// Round 8
// 7726.306 us; speedup vs baseline: 1.2853x; 1.0124x over previous
//
#include <hip/hip_runtime.h>

// Problem constants (shapes fixed by setup_inputs()).
#define B_ 1024
#define D_ 1024
#define F_ 32768
#define T_ 32
#define KSLOTS 32

// fp16x2 emulation: lo parts are stored scaled by 2^11 so they stay in f16 normal
// range (unscaled lo of xs elements ~1.5e-5 < f16 min normal 6.1e-5 -> flush risk).
#define LO_SCALE     2048.0f
#define LO_INV_SCALE 4.8828125e-4f

typedef _Float16 f16x8 __attribute__((ext_vector_type(8)));
typedef _Float16 f16x4 __attribute__((ext_vector_type(4)));
typedef float    f32x4 __attribute__((ext_vector_type(4)));

// ---------- packed argmax key: (sortable float << 32) | (0xFFFFFFFF - idx) ----------
__device__ __forceinline__ unsigned int fkey(float f) {
    unsigned int u = __float_as_uint(f);
    return (u & 0x80000000u) ? ~u : (u | 0x80000000u);
}
__device__ __forceinline__ unsigned long long packkey(float v, unsigned int n) {
    return ((unsigned long long)fkey(v) << 32) | (unsigned long long)(0xFFFFFFFFu - n);
}

// async global->LDS, 16B per lane. LDS dst is wave-uniform base; HW writes lane l at
// dst + l*16. Global src is per-lane.
__device__ __forceinline__ void async16(const void* g, void* l) {
    __builtin_amdgcn_global_load_lds(
        (const __attribute__((address_space(1))) unsigned int*)g,
        (__attribute__((address_space(3))) unsigned int*)l, 16, 0, 0);
}

__device__ __forceinline__ f32x4 mfma16(f16x8 a, f16x8 b, f32x4 c) {
    return __builtin_amdgcn_mfma_f32_16x16x32_f16(a, b, c, 0, 0, 0);
}

__device__ __forceinline__ void fsplit(float v, _Float16& h, _Float16& l) {
    h = (_Float16)v;
    l = (_Float16)((v - (float)h) * LO_SCALE);
}

// ---------------- one-time XS split: fp32 -> f16 hi + scaled f16 lo ----------------
__global__ __launch_bounds__(256) void split_xs_kernel(
    const float* __restrict__ XS, _Float16* __restrict__ hi, _Float16* __restrict__ lo)
{
    const size_t i = ((size_t)blockIdx.x * 256 + threadIdx.x) * 4;
    const float4 v = *(const float4*)(XS + i);
    f16x4 hv, lv;
    _Float16 h, l;
    fsplit(v.x, h, l); hv[0] = h; lv[0] = l;
    fsplit(v.y, h, l); hv[1] = h; lv[1] = l;
    fsplit(v.z, h, l); hv[2] = h; lv[2] = l;
    fsplit(v.w, h, l); hv[3] = h; lv[3] = l;
    *(f16x4*)(hi + i) = hv;
    *(f16x4*)(lo + i) = lv;
}

// ---------------------------- init: r = x (+f16 split), cnt = 0 ----------------------------
__global__ __launch_bounds__(256) void init_kernel(
    const float* __restrict__ X, float* __restrict__ Rres,
    _Float16* __restrict__ Rhi, _Float16* __restrict__ Rlo,
    int* __restrict__ a_cnt, unsigned long long* __restrict__ amax)
{
    const int b = blockIdx.x, tid = threadIdx.x;
    const size_t d4 = (size_t)b * D_ + tid * 4;
    const float4 v = *(const float4*)(X + d4);
    *(float4*)(Rres + d4) = v;
    f16x4 hv, lv; _Float16 h, l;
    fsplit(v.x, h, l); hv[0] = h; lv[0] = l;
    fsplit(v.y, h, l); hv[1] = h; lv[1] = l;
    fsplit(v.z, h, l); hv[2] = h; lv[2] = l;
    fsplit(v.w, h, l); hv[3] = h; lv[3] = l;
    *(f16x4*)(Rhi + d4) = hv;
    *(f16x4*)(Rlo + d4) = lv;
    if (tid == 0) { a_cnt[b] = 0; amax[b] = 0ull; }
}

// ------------------- MFMA fp16x2 GEMM (ip = r @ xs^T) + per-row argmax -------------------
// Tile 128x128, BK=32, 256 threads = 4 waves as 2x2 of 64x64.
// R8 = R7 + ONE change: k-slot rotation swizzle rot(r) = (r + (r>>2)) & 3 on the LDS
// tiles. R7's fragment read (16 rows @64B stride, fixed 16B k-slot) put 8 lanes on each
// of 2 bank-quads (8-way); rotating the slot per row with rot() spreads the 16 lanes
// over 8 bank-quads x 2 lanes = 2-way = free (m136). gl_lds writes linearly, so the
// rotation is applied by permuting each lane's GLOBAL source k-slot (skof, per-lane
// constant) and reading with the same rotation (lks, per-lane constant) — rule #21
// both-sides-or-neither. rot is mod-16 periodic; all row bases are multiples of 16.
// (R6's failed swizzle was confounded with the 32x32 shape change; this is the clean A/B.)
// Counted-vmcnt pipeline (T4) + XCD-bijective swizzle retained from R5/R7.
#define SPL1(H, L, I, V) { _Float16 _h; _Float16 _l; fsplit((V), _h, _l); H[I] = _h; L[I] = _l; }

#define WAIT_VM8()  { asm volatile("s_waitcnt vmcnt(8)" ::: "memory"); }
#define WAIT_VM0()  { asm volatile("s_waitcnt vmcnt(0)" ::: "memory"); }
#define BARRIER_PIN() { __builtin_amdgcn_s_barrier(); __builtin_amdgcn_sched_barrier(0); }

template <bool PRE>
__global__ __launch_bounds__(256, 2) void gemm16_argmax_kernel(
    const _Float16* __restrict__ Ahi, const _Float16* __restrict__ Alo,
    const _Float16* __restrict__ Bhi, const _Float16* __restrict__ Blo,
    const float* __restrict__ XSf,
    unsigned long long* __restrict__ amax)
{
    __shared__ __align__(16) _Float16 As[2][2][128][32];   // [buf][hi/lo][row][k] 32KB
    __shared__ __align__(16) _Float16 Bs[2][2][128][32];   // 32KB
    __shared__ unsigned long long red[128][2];             // 2KB

    const int tid  = threadIdx.x;
    const int wid  = tid >> 6, lane = tid & 63;
    const int orig = (int)blockIdx.x;                  // 0..2047, round-robins XCDs
    const int wgid = (orig & 7) * 256 + (orig >> 3);   // XCD-contiguous chunks (bijective)
    const int m0   = (wgid & 7) * 128;                 // bm fastest within a chunk
    const int n0   = (wgid >> 3) * 128;
    const int wm   = wid >> 1, wn = wid & 1;

    f32x4 acc[4][4], acc2[4][4];
#pragma unroll
    for (int i = 0; i < 4; ++i)
#pragma unroll
        for (int j = 0; j < 4; ++j) {
            acc[i][j]  = (f32x4){0.f, 0.f, 0.f, 0.f};
            acc2[i][j] = (f32x4){0.f, 0.f, 0.f, 0.f};
        }

    // staging: wave w owns rows [w*32, w*32+32) of each tile; 1KB chunk = 16 rows.
    // lane l lands at LDS row ro+(l>>2), phys slot (l&3). Source k-slot is permuted so
    // phys slot p of row r holds logical slot (p - rot(r)) & 3, rot(r) = (r + (r>>2)) & 3.
    const int srow = wid * 32 + (lane >> 2);
    const int u    = lane >> 2;                                        // row within chunk
    const int skof = 8 * (((lane & 3) - ((u + (u >> 2)) & 3)) & 3);    // f16 units
    const _Float16* gAh = Ahi + (size_t)(m0 + srow) * D_ + skof;
    const _Float16* gAl = Alo + (size_t)(m0 + srow) * D_ + skof;
    const _Float16* gBh = nullptr;
    const _Float16* gBl = nullptr;
    const float*    gBf = nullptr;
    if constexpr (PRE) {
        gBh = Bhi + (size_t)(n0 + srow) * D_ + skof;
        gBl = Blo + (size_t)(n0 + srow) * D_ + skof;
    } else {
        gBf = XSf + (size_t)(n0 + (tid >> 1)) * D_ + (tid & 1) * 16;
    }

    // fragment read: row base+(lane&15), logical k-octet q = lane>>4;
    // phys slot = (q + rot(row)) & 3 with rot depending only on lane&15 (bases %16==0).
    const int lrow = lane & 15;
    const int lks  = 8 * (((lane >> 4) + lrow + (lrow >> 2)) & 3);

    // ---- helpers ----
    auto stageAB = [&](int bb, int k0) {       // PRE: A+B, 8 async16 per wave
#pragma unroll
        for (int c = 0; c < 2; ++c) {
            const size_t go = (size_t)(c * 16) * D_ + k0;
            const int    ro = wid * 32 + c * 16;
            async16(gAh + go, &As[bb][0][ro][0]);
            async16(gAl + go, &As[bb][1][ro][0]);
            async16(gBh + go, &Bs[bb][0][ro][0]);
            async16(gBl + go, &Bs[bb][1][ro][0]);
        }
    };
    auto stageA = [&](int bb, int k0) {        // !PRE fallback: A only
#pragma unroll
        for (int c = 0; c < 2; ++c) {
            const size_t go = (size_t)(c * 16) * D_ + k0;
            const int    ro = wid * 32 + c * 16;
            async16(gAh + go, &As[bb][0][ro][0]);
            async16(gAl + go, &As[bb][1][ro][0]);
        }
    };
    float4 q0, q1, q2, q3;
    auto loadB = [&](int k0) {
        q0 = *(const float4*)(gBf + k0);
        q1 = *(const float4*)(gBf + k0 + 4);
        q2 = *(const float4*)(gBf + k0 + 8);
        q3 = *(const float4*)(gBf + k0 + 12);
    };
    auto writeB = [&](int bb) {                // split fp32 regs -> f16 hi/lo in LDS
        const int br = tid >> 1;
        const int uu = (tid & 1) * 2;          // logical slots uu, uu+1
        const int rt = (br + (br >> 2)) & 3;   // rot(br), mod-16 periodic
        const int p0 = 8 * ((uu + rt) & 3);
        const int p1 = 8 * ((uu + 1 + rt) & 3);
        f16x8 h0, l0, h1, l1;
        SPL1(h0, l0, 0, q0.x) SPL1(h0, l0, 1, q0.y) SPL1(h0, l0, 2, q0.z) SPL1(h0, l0, 3, q0.w)
        SPL1(h0, l0, 4, q1.x) SPL1(h0, l0, 5, q1.y) SPL1(h0, l0, 6, q1.z) SPL1(h0, l0, 7, q1.w)
        SPL1(h1, l1, 0, q2.x) SPL1(h1, l1, 1, q2.y) SPL1(h1, l1, 2, q2.z) SPL1(h1, l1, 3, q2.w)
        SPL1(h1, l1, 4, q3.x) SPL1(h1, l1, 5, q3.y) SPL1(h1, l1, 6, q3.z) SPL1(h1, l1, 7, q3.w)
        *(f16x8*)&Bs[bb][0][br][p0] = h0;
        *(f16x8*)&Bs[bb][0][br][p1] = h1;
        *(f16x8*)&Bs[bb][1][br][p0] = l0;
        *(f16x8*)&Bs[bb][1][br][p1] = l1;
    };
    auto compute = [&](int bb) {
        f16x8 ah[4], al[4], bh[4], bl[4];
#pragma unroll
        for (int i = 0; i < 4; ++i) {
            ah[i] = *(const f16x8*)&As[bb][0][wm * 64 + i * 16 + lrow][lks];
            al[i] = *(const f16x8*)&As[bb][1][wm * 64 + i * 16 + lrow][lks];
            bh[i] = *(const f16x8*)&Bs[bb][0][wn * 64 + i * 16 + lrow][lks];
            bl[i] = *(const f16x8*)&Bs[bb][1][wn * 64 + i * 16 + lrow][lks];
        }
#pragma unroll
        for (int i = 0; i < 4; ++i)
#pragma unroll
            for (int j = 0; j < 4; ++j) {
                acc[i][j]  = mfma16(ah[i], bh[j], acc[i][j]);
                acc2[i][j] = mfma16(ah[i], bl[j], acc2[i][j]);
                acc2[i][j] = mfma16(al[i], bh[j], acc2[i][j]);
            }
    };

    if constexpr (PRE) {
        // ---- counted-vmcnt pipeline: loads stay in flight across barriers ----
        stageAB(0, 0);
        WAIT_VM0();
        BARRIER_PIN();
        for (int k0 = 0; k0 < D_; k0 += 64) {
            // slice 0: stage k0+32 -> buf1, wait prev (buf0) loads, compute buf0
            if (k0 + 32 < D_) { stageAB(1, k0 + 32); WAIT_VM8(); }
            else              { WAIT_VM0(); }
            BARRIER_PIN();            // buf0 fully loaded for all waves
            compute(0);
            BARRIER_PIN();            // all waves' buf0 ds_reads retired
            // slice 1: stage k0+64 -> buf0, wait buf1 loads, compute buf1
            if (k0 + 64 < D_) { stageAB(0, k0 + 64); WAIT_VM8(); }
            else              { WAIT_VM0(); }
            BARRIER_PIN();
            compute(1);
            BARRIER_PIN();
        }
    } else {
        // ---- fallback (no pre-split XS): original drain-style dbuf loop ----
        loadB(0); stageA(0, 0); writeB(0);
        __syncthreads();
        for (int k0 = 0; k0 < D_; k0 += 64) {
            if (k0 + 32 < D_) { loadB(k0 + 32); stageA(1, k0 + 32); }
            compute(0);
            if (k0 + 32 < D_) writeB(1);
            __syncthreads();
            if (k0 + 64 < D_) { loadB(k0 + 64); stageA(0, k0 + 64); }
            compute(1);
            if (k0 + 64 < D_) writeB(0);
            __syncthreads();
        }
    }

    // ---- argmax epilogue. C/D layout: col = lane&15, row = (lane>>4)*4 + reg. ----
    const unsigned cb = (unsigned)(n0 + wn * 64 + (lane & 15));
#pragma unroll
    for (int mi = 0; mi < 4; ++mi) {
#pragma unroll
        for (int r = 0; r < 4; ++r) {
            unsigned long long best = 0ull;
#pragma unroll
            for (int j = 0; j < 4; ++j) {
                const float v = acc[mi][j][r] + acc2[mi][j][r] * LO_INV_SCALE;
                const unsigned long long key = packkey(v, cb + (unsigned)(j * 16));
                best = key > best ? key : best;
            }
            // reduce over the 16 lanes sharing this row set (lane>>4 fixed)
#pragma unroll
            for (int off = 1; off < 16; off <<= 1) {
                const unsigned long long o = __shfl_xor(best, off);
                best = o > best ? o : best;
            }
            if ((lane & 15) == 0)
                red[wm * 64 + mi * 16 + ((lane >> 4) << 2) + r][wn] = best;
        }
    }
    __syncthreads();
    if (tid < 128) {
        const unsigned long long b0 = red[tid][0], b1 = red[tid][1];
        atomicMax(&amax[m0 + tid], b0 > b1 ? b0 : b1);
    }
}

// ----------------- per-row sparse update: select, grad, step, relu, residual -----------------
// R7: all three D-passes vectorized to float4 (16B/lane, G13). Per-element math identical;
// only the wave-dot accumulation order shifts (~1e-6 fp noise, inside current margin).
__global__ __launch_bounds__(256) void update_kernel(
    const float* __restrict__ X, const float* __restrict__ XS,
    float* __restrict__ Rres,
    _Float16* __restrict__ Rhi, _Float16* __restrict__ Rlo,
    int* __restrict__ a_idx, float* __restrict__ a_w, int* __restrict__ a_cnt,
    unsigned long long* __restrict__ amax)
{
    const int b = blockIdx.x;
    const int tid = threadIdx.x;
    __shared__ float s_r[D_];
    __shared__ int   s_idx[33];
    __shared__ float s_w[33];
    __shared__ float s_g[33];
    __shared__ int   s_cnt;
    __shared__ float s_red[8];

    *(float4*)&s_r[tid * 4] = *(const float4*)(Rres + (size_t)b * D_ + tid * 4);

    if (tid == 0) {
        int cnt = a_cnt[b];
        for (int j = 0; j < cnt; ++j) { s_idx[j] = a_idx[b*KSLOTS + j]; s_w[j] = a_w[b*KSLOTS + j]; }
        unsigned long long key = amax[b];
        int ni = (int)(0xFFFFFFFFu - (unsigned int)(key & 0xFFFFFFFFull));
        bool found = false;
        for (int j = 0; j < cnt; ++j) found = found || (s_idx[j] == ni);
        if (!found) {  // insert keeping indices ascending (matches numpy's sum-over-f order)
            int p = cnt;
            while (p > 0 && s_idx[p-1] > ni) { s_idx[p] = s_idx[p-1]; s_w[p] = s_w[p-1]; --p; }
            s_idx[p] = ni; s_w[p] = 0.f; ++cnt;
        }
        s_cnt = cnt;
    }
    __syncthreads();
    const int cnt = s_cnt;
    const int wave = tid >> 6, lane = tid & 63;

    // grad_j = <r, xs[idx_j]> for each selected atom (one wave per atom, round-robin)
    for (int j = wave; j < cnt; j += 4) {
        const float* xr = XS + (size_t)s_idx[j] * D_;
        float sum = 0.f;
#pragma unroll
        for (int i = 0; i < 4; ++i) {
            const int d = lane * 4 + i * 256;
            const float4 xv = *(const float4*)(xr + d);
            const float4 rv = *(const float4*)(&s_r[d]);
            sum = fmaf(rv.x, xv.x, sum); sum = fmaf(rv.y, xv.y, sum);
            sum = fmaf(rv.z, xv.z, sum); sum = fmaf(rv.w, xv.w, sum);
        }
        for (int off = 32; off > 0; off >>= 1) sum += __shfl_down(sum, off);
        if (lane == 0) s_g[j] = sum;
    }
    __syncthreads();

    // c = grad @ xs (only over active atoms, ascending index); reduce c.c and c.r
    const int d4 = tid * 4;
    float cs = 0.f, cr = 0.f;
    {
        float4 cv = {0.f, 0.f, 0.f, 0.f};
        for (int j = 0; j < cnt; ++j) {
            const float g = s_g[j];
            const float4 xv = *(const float4*)(XS + (size_t)s_idx[j] * D_ + d4);
            cv.x = fmaf(g, xv.x, cv.x); cv.y = fmaf(g, xv.y, cv.y);
            cv.z = fmaf(g, xv.z, cv.z); cv.w = fmaf(g, xv.w, cv.w);
        }
        const float4 rv = *(const float4*)(&s_r[d4]);
        cs = fmaf(cv.x, cv.x, cs); cr = fmaf(cv.x, rv.x, cr);
        cs = fmaf(cv.y, cv.y, cs); cr = fmaf(cv.y, rv.y, cr);
        cs = fmaf(cv.z, cv.z, cs); cr = fmaf(cv.z, rv.z, cr);
        cs = fmaf(cv.w, cv.w, cs); cr = fmaf(cv.w, rv.w, cr);
    }
    for (int off = 32; off > 0; off >>= 1) { cs += __shfl_down(cs, off); cr += __shfl_down(cr, off); }
    if (lane == 0) { s_red[wave] = cs; s_red[4 + wave] = cr; }
    __syncthreads();

    if (tid == 0) {
        const float cs_t = s_red[0] + s_red[1] + s_red[2] + s_red[3];
        const float cr_t = s_red[4] + s_red[5] + s_red[6] + s_red[7];
        const float ss = cr_t / fmaxf(cs_t, 1e-3f);
        int nc = 0;
        for (int j = 0; j < cnt; ++j) {           // weights = relu(w + ss*grad), drop zeros
            float nw = s_w[j] + ss * s_g[j];
            if (nw > 0.f) { s_idx[nc] = s_idx[j]; s_w[nc] = nw; ++nc; }
        }
        s_cnt = nc;
        a_cnt[b] = nc;
        for (int j = 0; j < nc; ++j) { a_idx[b*KSLOTS + j] = s_idx[j]; a_w[b*KSLOTS + j] = s_w[j]; }
        amax[b] = 0ull;                            // reset for next step's GEMM
    }
    __syncthreads();
    const int nc = s_cnt;

    // fresh residual: r = x - sum_j w_j * xs[idx_j]; also write the f16 hi/lo split
    {
        float4 s = {0.f, 0.f, 0.f, 0.f};
        for (int j = 0; j < nc; ++j) {
            const float w = s_w[j];
            const float4 xv = *(const float4*)(XS + (size_t)s_idx[j] * D_ + d4);
            s.x = fmaf(w, xv.x, s.x); s.y = fmaf(w, xv.y, s.y);
            s.z = fmaf(w, xv.z, s.z); s.w = fmaf(w, xv.w, s.w);
        }
        const size_t o = (size_t)b * D_ + d4;
        const float4 xv = *(const float4*)(X + o);
        float4 rv;
        rv.x = xv.x - s.x; rv.y = xv.y - s.y; rv.z = xv.z - s.z; rv.w = xv.w - s.w;
        *(float4*)(Rres + o) = rv;
        f16x4 hv, lv; _Float16 h, l;
        fsplit(rv.x, h, l); hv[0] = h; lv[0] = l;
        fsplit(rv.y, h, l); hv[1] = h; lv[1] = l;
        fsplit(rv.z, h, l); hv[2] = h; lv[2] = l;
        fsplit(rv.w, h, l); hv[3] = h; lv[3] = l;
        *(f16x4*)(Rhi + o) = hv;
        *(f16x4*)(Rlo + o) = lv;
    }
}

// ----------------- finalize: top_k, decode x/y, losses, write outputs -----------------
__global__ __launch_bounds__(256) void finalize_kernel(
    const float* __restrict__ Y,
    const float* __restrict__ XS, const float* __restrict__ YS,
    const int* __restrict__ a_idx, const float* __restrict__ a_w, const int* __restrict__ a_cnt,
    float* __restrict__ out)
{
    const int b = blockIdx.x, tid = threadIdx.x;
    __shared__ int   s_idx[KSLOTS];
    __shared__ float s_w[KSLOTS];
    __shared__ int   o_idx[KSLOTS];
    __shared__ float o_w[KSLOTS];
    __shared__ float s_red[4];

    if (tid == 0) {
        int cnt = a_cnt[b];
        for (int j = 0; j < cnt; ++j) { s_idx[j] = a_idx[b*KSLOTS + j]; s_w[j] = a_w[b*KSLOTS + j]; }
        // insertion sort: desc weight, ties -> ascending index (lax.top_k semantics)
        for (int i = 1; i < cnt; ++i) {
            int ii = s_idx[i]; float ww = s_w[i];
            int p = i - 1;
            while (p >= 0 && (s_w[p] < ww || (s_w[p] == ww && s_idx[p] > ii))) {
                s_w[p+1] = s_w[p]; s_idx[p+1] = s_idx[p]; --p;
            }
            s_w[p+1] = ww; s_idx[p+1] = ii;
        }
        for (int j = 0; j < cnt; ++j) { o_idx[j] = s_idx[j]; o_w[j] = s_w[j]; }
        // pad remaining slots with the smallest indices whose weight is zero
        int p = cnt, f = 0;
        while (p < KSLOTS) {
            bool member = false;
            for (int j = 0; j < cnt; ++j) member = member || (s_idx[j] == f);
            if (!member) { o_idx[p] = f; o_w[p] = 0.f; ++p; }
            ++f;
        }
    }
    __syncthreads();

    if (tid < KSLOTS) {
        out[(size_t)b*KSLOTS + tid] = o_w[tid];
        out[32768 + (size_t)b*KSLOTS + tid] = (float)o_idx[tid];   // harness reads fp32
    }

    // decode pass: float4 (one 4-elem chunk per thread; 256*4 = 1024 = D_)
    const int d4 = tid * 4;
    float4 xr = {0.f, 0.f, 0.f, 0.f}, yr = {0.f, 0.f, 0.f, 0.f};
#pragma unroll
    for (int k = 0; k < KSLOTS; ++k) {
        const float w = o_w[k];
        const size_t off = (size_t)o_idx[k] * D_ + d4;
        const float4 xv = *(const float4*)(XS + off);
        const float4 yv = *(const float4*)(YS + off);
        xr.x = fmaf(w, xv.x, xr.x); xr.y = fmaf(w, xv.y, xr.y);
        xr.z = fmaf(w, xv.z, xr.z); xr.w = fmaf(w, xv.w, xr.w);
        yr.x = fmaf(w, yv.x, yr.x); yr.y = fmaf(w, yv.y, yr.y);
        yr.z = fmaf(w, yv.z, yr.z); yr.w = fmaf(w, yv.w, yr.w);
    }
    *(float4*)(out + 65536 + (size_t)b*D_ + d4) = xr;
    *(float4*)(out + 65536 + 1048576 + (size_t)b*D_ + d4) = yr;
    const float4 yv = *(const float4*)(Y + (size_t)b*D_ + d4);
    float lsum = 0.f;
    {
        const float e0 = yr.x - yv.x, e1 = yr.y - yv.y, e2 = yr.z - yv.z, e3 = yr.w - yv.w;
        lsum = fmaf(e0, e0, lsum); lsum = fmaf(e1, e1, lsum);
        lsum = fmaf(e2, e2, lsum); lsum = fmaf(e3, e3, lsum);
    }
    const int wave = tid >> 6, lane = tid & 63;
    for (int off = 32; off > 0; off >>= 1) lsum += __shfl_down(lsum, off);
    if (lane == 0) s_red[wave] = lsum;
    __syncthreads();
    if (tid == 0) out[65536 + 2097152 + b] = s_red[0] + s_red[1] + s_red[2] + s_red[3];
}

extern "C" void kernel_launch(void* const* d_in, const int* in_sizes, int n_in,
                              void* d_out, int out_size, void* d_ws, size_t ws_size,
                              hipStream_t stream) {
    (void)in_sizes; (void)n_in; (void)out_size;
    const float* x  = (const float*)d_in[0];
    const float* y  = (const float*)d_in[1];
    const float* xs = (const float*)d_in[2];
    const float* ys = (const float*)d_in[3];
    // d_in[4] = target_l0 (hardcoded 32; shapes are fixed)
    float* out = (float*)d_out;

    // workspace layout:
    //   0        Rres fp32            4 MB
    //   4 MB     Rhi  f16             2 MB
    //   6 MB     Rlo  f16 (scaled)    2 MB
    //   8 MB     amax                 8 KB
    //   +8K      a_cnt                4 KB
    //   +12K     a_idx              128 KB
    //   +140K    a_w                128 KB
    //   16 MB    XShi f16            64 MB   (only if ws_size >= 144 MB)
    //   80 MB    XSlo f16 (scaled)   64 MB
    char* ws = (char*)d_ws;
    float*              Rres  = (float*)(ws);
    _Float16*           Rhi   = (_Float16*)(ws + ((size_t)4 << 20));
    _Float16*           Rlo   = (_Float16*)(ws + ((size_t)6 << 20));
    unsigned long long* amax  = (unsigned long long*)(ws + ((size_t)8 << 20));
    int*                a_cnt = (int*)(ws + ((size_t)8 << 20) + 8192);
    int*                a_idx = (int*)(ws + ((size_t)8 << 20) + 8192 + 4096);
    float*              a_w   = (float*)(ws + ((size_t)8 << 20) + 8192 + 4096 + 131072);
    _Float16*           XShi  = (_Float16*)(ws + ((size_t)16 << 20));
    _Float16*           XSlo  = (_Float16*)(ws + ((size_t)80 << 20));
    const bool big = ws_size >= ((size_t)144 << 20);

    if (big) split_xs_kernel<<<(F_ * D_) / 1024, 256, 0, stream>>>(xs, XShi, XSlo);
    init_kernel<<<B_, 256, 0, stream>>>(x, Rres, Rhi, Rlo, a_cnt, amax);

    for (int t = 0; t < T_; ++t) {
        if (big)
            gemm16_argmax_kernel<true ><<<dim3(2048), 256, 0, stream>>>(Rhi, Rlo, XShi, XSlo, xs, amax);
        else
            gemm16_argmax_kernel<false><<<dim3(2048), 256, 0, stream>>>(Rhi, Rlo, nullptr, nullptr, xs, amax);
        update_kernel<<<B_, 256, 0, stream>>>(x, xs, Rres, Rhi, Rlo, a_idx, a_w, a_cnt, amax);
    }
    finalize_kernel<<<B_, 256, 0, stream>>>(y, xs, ys, a_idx, a_w, a_cnt, out);
}